// Round 2
// baseline (187.221 us; speedup 1.0000x reference)
//
#include <hip/hip_runtime.h>
#include <math.h>

#define HID    1024
#define VOCAB  50257
#define MAXLEN 2048

// ---------------- ws layout (float indices) ----------------
// [0,     2048)  scores
// [2048,  4096)  attn_weights (ws copy)
// [4096,  5120)  attn_applied
// [5120,  6144)  x (post-relu)
// [6144,  9216)  gi
// [9216, 12288)  gh
// [12288,13312)  h_new (ws copy, float4-aligned)
// [13312]        max cell (encoded uint)
// [13313]        lse
// [13440,13568)  sum-exp partials (128)
// [16384,81920)  attn partials (64 chunks x 1024)
#define WS_SCORES    0
#define WS_ATTNW     2048
#define WS_APPLIED   4096
#define WS_X         5120
#define WS_GI        6144
#define WS_GH        9216
#define WS_HNEW      12288
#define WS_MAXCELL   13312
#define WS_LSE       13313
#define WS_SUMPART   13440
#define WS_PARTIALS  16384

__device__ inline float wave_reduce_sum(float v) {
    #pragma unroll
    for (int m = 32; m > 0; m >>= 1) v += __shfl_xor(v, m, 64);
    return v;
}

__device__ inline unsigned int enc_float(float f) {
    unsigned int b = __float_as_uint(f);
    unsigned int mask = (b & 0x80000000u) ? 0xFFFFFFFFu : 0x80000000u;
    return b ^ mask;
}
__device__ inline float dec_float(unsigned int e) {
    unsigned int b = (e & 0x80000000u) ? (e ^ 0x80000000u) : ~e;
    return __uint_as_float(b);
}

// K1: scores[l] = dot(cat(embedded, h), attn_W[l]) + attn_b[l], one wave per row
__global__ void k_attn_scores(const float* __restrict__ emb, const int* __restrict__ tok,
                              const float* __restrict__ hidden,
                              const float* __restrict__ attn_W, const float* __restrict__ attn_b,
                              float* __restrict__ scores) {
    int gtid = blockIdx.x * blockDim.x + threadIdx.x;
    int row = gtid >> 6, lane = gtid & 63;
    if (row >= MAXLEN) return;
    const float* erow = emb + (size_t)tok[0] * HID;
    const float* wrow = attn_W + (size_t)row * (2 * HID);
    float acc = 0.f;
    #pragma unroll
    for (int i = 0; i < 8; ++i) {
        int k = i * 256 + lane * 4;
        float4 w = *(const float4*)(wrow + k);
        float4 c = (k < HID) ? *(const float4*)(erow + k)
                             : *(const float4*)(hidden + (k - HID));
        acc += w.x * c.x + w.y * c.y + w.z * c.z + w.w * c.w;
    }
    acc = wave_reduce_sum(acc);
    if (lane == 0) scores[row] = acc + attn_b[row];
}

// K2: softmax over 2048 scores -> attn_weights (d_out region + ws copy)
__global__ __launch_bounds__(1024) void k_softmax2048(const float* __restrict__ scores,
                                                      float* __restrict__ out_w,
                                                      float* __restrict__ ws_w) {
    __shared__ float sm[1024];
    int t = threadIdx.x;
    float s0 = scores[t], s1 = scores[t + 1024];
    sm[t] = fmaxf(s0, s1);
    __syncthreads();
    for (int s = 512; s > 0; s >>= 1) { if (t < s) sm[t] = fmaxf(sm[t], sm[t + s]); __syncthreads(); }
    float m = sm[0];
    __syncthreads();
    float e0 = expf(s0 - m), e1 = expf(s1 - m);
    sm[t] = e0 + e1;
    __syncthreads();
    for (int s = 512; s > 0; s >>= 1) { if (t < s) sm[t] += sm[t + s]; __syncthreads(); }
    float inv = 1.f / sm[0];
    out_w[t] = e0 * inv; out_w[t + 1024] = e1 * inv;
    ws_w[t]  = e0 * inv; ws_w[t + 1024]  = e1 * inv;
}

// K3: partial column-weighted sums of encoder_outputs; 64 blocks x 32 rows
__global__ void k_attn_apply_partial(const float* __restrict__ E, const float* __restrict__ w,
                                     float* __restrict__ partials) {
    int b = blockIdx.x, t = threadIdx.x;
    int j = t * 4;
    float4 acc = make_float4(0.f, 0.f, 0.f, 0.f);
    int r0 = b * 32;
    for (int r = 0; r < 32; ++r) {
        float wr = w[r0 + r];
        float4 e = *(const float4*)(E + (size_t)(r0 + r) * HID + j);
        acc.x += wr * e.x; acc.y += wr * e.y; acc.z += wr * e.z; acc.w += wr * e.w;
    }
    *(float4*)(partials + (size_t)b * HID + j) = acc;
}

// K4: reduce 64 partial rows -> attn_applied[1024]
__global__ void k_attn_apply_reduce(const float* __restrict__ partials, float* __restrict__ applied) {
    int j = blockIdx.x * blockDim.x + threadIdx.x;
    float acc = 0.f;
    for (int c = 0; c < 64; ++c) acc += partials[c * HID + j];
    applied[j] = acc;
}

// K5: x = relu(comb_W @ cat(embedded, attn_applied) + comb_b), one wave per row
__global__ void k_comb(const float* __restrict__ emb, const int* __restrict__ tok,
                       const float* __restrict__ applied,
                       const float* __restrict__ comb_W, const float* __restrict__ comb_b,
                       float* __restrict__ x) {
    int gtid = blockIdx.x * blockDim.x + threadIdx.x;
    int row = gtid >> 6, lane = gtid & 63;
    if (row >= HID) return;
    const float* erow = emb + (size_t)tok[0] * HID;
    const float* wrow = comb_W + (size_t)row * (2 * HID);
    float acc = 0.f;
    #pragma unroll
    for (int i = 0; i < 8; ++i) {
        int k = i * 256 + lane * 4;
        float4 w = *(const float4*)(wrow + k);
        float4 c = (k < HID) ? *(const float4*)(erow + k)
                             : *(const float4*)(applied + (k - HID));
        acc += w.x * c.x + w.y * c.y + w.z * c.z + w.w * c.w;
    }
    acc = wave_reduce_sum(acc);
    if (lane == 0) x[row] = fmaxf(acc + comb_b[row], 0.f);
}

// K6: gi = W_ih@x + b_ih, gh = W_hh@h + b_hh; 6144 rows, one wave per row
__global__ void k_gru_gemv(const float* __restrict__ W_ih, const float* __restrict__ W_hh,
                           const float* __restrict__ b_ih, const float* __restrict__ b_hh,
                           const float* __restrict__ x, const float* __restrict__ h,
                           float* __restrict__ gi, float* __restrict__ gh) {
    int gtid = blockIdx.x * blockDim.x + threadIdx.x;
    int row = gtid >> 6, lane = gtid & 63;
    if (row >= 6 * HID) return;
    const float* wrow; const float* vec;
    if (row < 3 * HID) { wrow = W_ih + (size_t)row * HID; vec = x; }
    else               { wrow = W_hh + (size_t)(row - 3 * HID) * HID; vec = h; }
    float acc = 0.f;
    #pragma unroll
    for (int i = 0; i < 4; ++i) {
        int k = i * 256 + lane * 4;
        float4 w = *(const float4*)(wrow + k);
        float4 c = *(const float4*)(vec + k);
        acc += w.x * c.x + w.y * c.y + w.z * c.z + w.w * c.w;
    }
    acc = wave_reduce_sum(acc);
    if (lane == 0) {
        if (row < 3 * HID) gi[row] = acc + b_ih[row];
        else               gh[row - 3 * HID] = acc + b_hh[row - 3 * HID];
    }
}

// K7: GRU gates -> h_new (d_out + ws copy); also init the max cell
__global__ void k_gru_gate(const float* __restrict__ gi, const float* __restrict__ gh,
                           const float* __restrict__ h,
                           float* __restrict__ hnew_out, float* __restrict__ hnew_ws,
                           unsigned int* __restrict__ maxcell) {
    int i = blockIdx.x * blockDim.x + threadIdx.x;
    float r = 1.f / (1.f + expf(-(gi[i] + gh[i])));
    float z = 1.f / (1.f + expf(-(gi[i + HID] + gh[i + HID])));
    float n = tanhf(gi[i + 2 * HID] + r * gh[i + 2 * HID]);
    float hn = (1.f - z) * n + z * h[i];
    hnew_out[i] = hn;
    hnew_ws[i]  = hn;
    if (i == 0) *maxcell = 0u;  // encodes below any finite float
}

// K8: logits[v] = dot(h_new, out_W[v]) + out_b[v]; one wave per row; block max -> atomicMax
__global__ void k_logits(const float* __restrict__ hnew, const float* __restrict__ out_W,
                         const float* __restrict__ out_b,
                         float* __restrict__ logits, unsigned int* __restrict__ maxcell) {
    __shared__ float wmax[4];
    int wib = threadIdx.x >> 6, lane = threadIdx.x & 63;
    int row = blockIdx.x * 4 + wib;
    float acc = 0.f;
    if (row < VOCAB) {
        const float* wrow = out_W + (size_t)row * HID;
        #pragma unroll
        for (int i = 0; i < 4; ++i) {
            int k = i * 256 + lane * 4;
            float4 w = *(const float4*)(wrow + k);
            float4 c = *(const float4*)(hnew + k);
            acc += w.x * c.x + w.y * c.y + w.z * c.z + w.w * c.w;
        }
        acc = wave_reduce_sum(acc);
        if (lane == 0) { acc += out_b[row]; logits[row] = acc; }
    }
    if (lane == 0) wmax[wib] = (row < VOCAB) ? acc : -INFINITY;
    __syncthreads();
    if (threadIdx.x == 0) {
        float m = fmaxf(fmaxf(wmax[0], wmax[1]), fmaxf(wmax[2], wmax[3]));
        atomicMax(maxcell, enc_float(m));
    }
}

// K9: partial sums of exp(logit - max); 128 blocks
__global__ void k_sumexp(const float* __restrict__ logits, const unsigned int* __restrict__ maxcell,
                         float* __restrict__ partials) {
    __shared__ float sm[4];
    float m = dec_float(*maxcell);
    float acc = 0.f;
    for (int v = blockIdx.x * blockDim.x + threadIdx.x; v < VOCAB; v += gridDim.x * blockDim.x)
        acc += expf(logits[v] - m);
    acc = wave_reduce_sum(acc);
    int wib = threadIdx.x >> 6, lane = threadIdx.x & 63;
    if (lane == 0) sm[wib] = acc;
    __syncthreads();
    if (threadIdx.x == 0) partials[blockIdx.x] = sm[0] + sm[1] + sm[2] + sm[3];
}

// K10: lse = max + log(sum(partials))
__global__ void k_finalize(const float* __restrict__ partials, const unsigned int* __restrict__ maxcell,
                           float* __restrict__ lse) {
    __shared__ float a[2];
    float v = partials[threadIdx.x];  // 128 threads
    v = wave_reduce_sum(v);
    if ((threadIdx.x & 63) == 0) a[threadIdx.x >> 6] = v;
    __syncthreads();
    if (threadIdx.x == 0) lse[0] = dec_float(*maxcell) + logf(a[0] + a[1]);
}

// K11: out[v] = logits[v] - lse  (in place on d_out)
__global__ void k_writeout(float* __restrict__ out, const float* __restrict__ lse) {
    int v = blockIdx.x * blockDim.x + threadIdx.x;
    if (v < VOCAB) out[v] -= lse[0];
}

extern "C" void kernel_launch(void* const* d_in, const int* in_sizes, int n_in,
                              void* d_out, int out_size, void* d_ws, size_t ws_size,
                              hipStream_t stream) {
    const int*   tok     = (const int*)d_in[0];
    const float* hidden  = (const float*)d_in[1];
    const float* E       = (const float*)d_in[2];
    const float* emb     = (const float*)d_in[3];
    const float* attn_W  = (const float*)d_in[4];
    const float* attn_b  = (const float*)d_in[5];
    const float* comb_W  = (const float*)d_in[6];
    const float* comb_b  = (const float*)d_in[7];
    const float* W_ih    = (const float*)d_in[8];
    const float* W_hh    = (const float*)d_in[9];
    const float* b_ih    = (const float*)d_in[10];
    const float* b_hh    = (const float*)d_in[11];
    const float* out_W   = (const float*)d_in[12];
    const float* out_b   = (const float*)d_in[13];

    float* out       = (float*)d_out;          // [0, VOCAB): log-probs
    float* hnew_out  = out + VOCAB;            // [VOCAB, VOCAB+HID): h_new
    float* attnw_out = out + VOCAB + HID;      // [.., +MAXLEN): attn_weights

    float* ws        = (float*)d_ws;
    float* scores    = ws + WS_SCORES;
    float* attnw_ws  = ws + WS_ATTNW;
    float* applied   = ws + WS_APPLIED;
    float* x         = ws + WS_X;
    float* gi        = ws + WS_GI;
    float* gh        = ws + WS_GH;
    float* hnew_ws   = ws + WS_HNEW;
    unsigned int* maxcell = (unsigned int*)(ws + WS_MAXCELL);
    float* lse       = ws + WS_LSE;
    float* sumpart   = ws + WS_SUMPART;
    float* partials  = ws + WS_PARTIALS;

    k_attn_scores<<<MAXLEN / 4, 256, 0, stream>>>(emb, tok, hidden, attn_W, attn_b, scores);
    k_softmax2048<<<1, 1024, 0, stream>>>(scores, attnw_out, attnw_ws);
    k_attn_apply_partial<<<64, 256, 0, stream>>>(E, attnw_ws, partials);
    k_attn_apply_reduce<<<4, 256, 0, stream>>>(partials, applied);
    k_comb<<<HID / 4, 256, 0, stream>>>(emb, tok, applied, comb_W, comb_b, x);
    k_gru_gemv<<<(6 * HID) / 4, 256, 0, stream>>>(W_ih, W_hh, b_ih, b_hh, x, hidden, gi, gh);
    k_gru_gate<<<HID / 256, 256, 0, stream>>>(gi, gh, hidden, hnew_out, hnew_ws, maxcell);
    k_logits<<<(VOCAB + 3) / 4, 256, 0, stream>>>(hnew_ws, out_W, out_b, out, maxcell);
    k_sumexp<<<128, 256, 0, stream>>>(out, maxcell, sumpart);
    k_finalize<<<1, 128, 0, stream>>>(sumpart, maxcell, lse);
    k_writeout<<<(VOCAB + 255) / 256, 256, 0, stream>>>(out, lse);
}

// Round 4
// 73.461 us; speedup vs baseline: 2.5486x; 2.5486x over previous
//
#include <hip/hip_runtime.h>
#include <math.h>

#define HID    1024
#define VOCAB  50257
#define MAXLEN 2048
#define LOGIT_BLOCKS ((VOCAB + 3) / 4)   // 12565

// ---------------- ws layout (float indices) ----------------
// [0,     2048)  scores
// [2048,  4096)  attn_weights (ws copy)
// [4096,  5120)  attn_applied
// [5120,  6144)  x (post-relu)
// [6144,  9216)  gi
// [9216, 12288)  gh
// [12288,13312)  h_new (ws copy, float4-aligned)
// [13312]        global max (float)
// [13313]        lse
// [13440,13568)  sum-exp partials (128)
// [16384,81920)  attn partials (64 x 1024); reused later as blockmax[12565]
#define WS_SCORES    0
#define WS_ATTNW     2048
#define WS_APPLIED   4096
#define WS_X         5120
#define WS_GI        6144
#define WS_GH        9216
#define WS_HNEW      12288
#define WS_MAXCELL   13312
#define WS_LSE       13313
#define WS_SUMPART   13440
#define WS_PARTIALS  16384

__device__ inline float wave_reduce_sum(float v) {
    #pragma unroll
    for (int m = 32; m > 0; m >>= 1) v += __shfl_xor(v, m, 64);
    return v;
}

// K1: scores[l] = dot(cat(embedded, h), attn_W[l]) + attn_b[l], one wave per row
__global__ void k_attn_scores(const float* __restrict__ emb, const int* __restrict__ tok,
                              const float* __restrict__ hidden,
                              const float* __restrict__ attn_W, const float* __restrict__ attn_b,
                              float* __restrict__ scores) {
    int gtid = blockIdx.x * blockDim.x + threadIdx.x;
    int row = gtid >> 6, lane = gtid & 63;
    if (row >= MAXLEN) return;
    const float* erow = emb + (size_t)tok[0] * HID;
    const float* wrow = attn_W + (size_t)row * (2 * HID);
    float acc = 0.f;
    #pragma unroll
    for (int i = 0; i < 8; ++i) {
        int k = i * 256 + lane * 4;
        float4 w = *(const float4*)(wrow + k);
        float4 c = (k < HID) ? *(const float4*)(erow + k)
                             : *(const float4*)(hidden + (k - HID));
        acc += w.x * c.x + w.y * c.y + w.z * c.z + w.w * c.w;
    }
    acc = wave_reduce_sum(acc);
    if (lane == 0) scores[row] = acc + attn_b[row];
}

// K2: softmax over 2048 scores -> attn_weights (d_out region + ws copy)
__global__ __launch_bounds__(1024) void k_softmax2048(const float* __restrict__ scores,
                                                      float* __restrict__ out_w,
                                                      float* __restrict__ ws_w) {
    __shared__ float sm[1024];
    int t = threadIdx.x;
    float s0 = scores[t], s1 = scores[t + 1024];
    sm[t] = fmaxf(s0, s1);
    __syncthreads();
    for (int s = 512; s > 0; s >>= 1) { if (t < s) sm[t] = fmaxf(sm[t], sm[t + s]); __syncthreads(); }
    float m = sm[0];
    __syncthreads();
    float e0 = expf(s0 - m), e1 = expf(s1 - m);
    sm[t] = e0 + e1;
    __syncthreads();
    for (int s = 512; s > 0; s >>= 1) { if (t < s) sm[t] += sm[t + s]; __syncthreads(); }
    float inv = 1.f / sm[0];
    out_w[t] = e0 * inv; out_w[t + 1024] = e1 * inv;
    ws_w[t]  = e0 * inv; ws_w[t + 1024]  = e1 * inv;
}

// K3: partial column-weighted sums of encoder_outputs; 64 blocks x 32 rows
__global__ void k_attn_apply_partial(const float* __restrict__ E, const float* __restrict__ w,
                                     float* __restrict__ partials) {
    int b = blockIdx.x, t = threadIdx.x;
    int j = t * 4;
    float4 acc = make_float4(0.f, 0.f, 0.f, 0.f);
    int r0 = b * 32;
    for (int r = 0; r < 32; ++r) {
        float wr = w[r0 + r];
        float4 e = *(const float4*)(E + (size_t)(r0 + r) * HID + j);
        acc.x += wr * e.x; acc.y += wr * e.y; acc.z += wr * e.z; acc.w += wr * e.w;
    }
    *(float4*)(partials + (size_t)b * HID + j) = acc;
}

// K4: reduce 64 partial rows -> attn_applied[1024]
__global__ void k_attn_apply_reduce(const float* __restrict__ partials, float* __restrict__ applied) {
    int j = blockIdx.x * blockDim.x + threadIdx.x;
    float acc = 0.f;
    for (int c = 0; c < 64; ++c) acc += partials[c * HID + j];
    applied[j] = acc;
}

// K5: x = relu(comb_W @ cat(embedded, attn_applied) + comb_b), one wave per row
__global__ void k_comb(const float* __restrict__ emb, const int* __restrict__ tok,
                       const float* __restrict__ applied,
                       const float* __restrict__ comb_W, const float* __restrict__ comb_b,
                       float* __restrict__ x) {
    int gtid = blockIdx.x * blockDim.x + threadIdx.x;
    int row = gtid >> 6, lane = gtid & 63;
    if (row >= HID) return;
    const float* erow = emb + (size_t)tok[0] * HID;
    const float* wrow = comb_W + (size_t)row * (2 * HID);
    float acc = 0.f;
    #pragma unroll
    for (int i = 0; i < 8; ++i) {
        int k = i * 256 + lane * 4;
        float4 w = *(const float4*)(wrow + k);
        float4 c = (k < HID) ? *(const float4*)(erow + k)
                             : *(const float4*)(applied + (k - HID));
        acc += w.x * c.x + w.y * c.y + w.z * c.z + w.w * c.w;
    }
    acc = wave_reduce_sum(acc);
    if (lane == 0) x[row] = fmaxf(acc + comb_b[row], 0.f);
}

// K6: gi = W_ih@x + b_ih, gh = W_hh@h + b_hh; 6144 rows, one wave per row
__global__ void k_gru_gemv(const float* __restrict__ W_ih, const float* __restrict__ W_hh,
                           const float* __restrict__ b_ih, const float* __restrict__ b_hh,
                           const float* __restrict__ x, const float* __restrict__ h,
                           float* __restrict__ gi, float* __restrict__ gh) {
    int gtid = blockIdx.x * blockDim.x + threadIdx.x;
    int row = gtid >> 6, lane = gtid & 63;
    if (row >= 6 * HID) return;
    const float* wrow; const float* vec;
    if (row < 3 * HID) { wrow = W_ih + (size_t)row * HID; vec = x; }
    else               { wrow = W_hh + (size_t)(row - 3 * HID) * HID; vec = h; }
    float acc = 0.f;
    #pragma unroll
    for (int i = 0; i < 4; ++i) {
        int k = i * 256 + lane * 4;
        float4 w = *(const float4*)(wrow + k);
        float4 c = *(const float4*)(vec + k);
        acc += w.x * c.x + w.y * c.y + w.z * c.z + w.w * c.w;
    }
    acc = wave_reduce_sum(acc);
    if (lane == 0) {
        if (row < 3 * HID) gi[row] = acc + b_ih[row];
        else               gh[row - 3 * HID] = acc + b_hh[row - 3 * HID];
    }
}

// K7: GRU gates -> h_new (d_out + ws copy)
__global__ void k_gru_gate(const float* __restrict__ gi, const float* __restrict__ gh,
                           const float* __restrict__ h,
                           float* __restrict__ hnew_out, float* __restrict__ hnew_ws) {
    int i = blockIdx.x * blockDim.x + threadIdx.x;
    float r = 1.f / (1.f + expf(-(gi[i] + gh[i])));
    float z = 1.f / (1.f + expf(-(gi[i + HID] + gh[i + HID])));
    float n = tanhf(gi[i + 2 * HID] + r * gh[i + 2 * HID]);
    float hn = (1.f - z) * n + z * h[i];
    hnew_out[i] = hn;
    hnew_ws[i]  = hn;
}

// K8: logits[v] = dot(h_new, out_W[v]) + out_b[v]; one wave per row; per-block max -> blockmax[]
__global__ void k_logits(const float* __restrict__ hnew, const float* __restrict__ out_W,
                         const float* __restrict__ out_b,
                         float* __restrict__ logits, float* __restrict__ blockmax) {
    __shared__ float wmax[4];
    int wib = threadIdx.x >> 6, lane = threadIdx.x & 63;
    int row = blockIdx.x * 4 + wib;
    float acc = 0.f;
    if (row < VOCAB) {
        const float* wrow = out_W + (size_t)row * HID;
        #pragma unroll
        for (int i = 0; i < 4; ++i) {
            int k = i * 256 + lane * 4;
            float4 w = *(const float4*)(wrow + k);
            float4 c = *(const float4*)(hnew + k);
            acc += w.x * c.x + w.y * c.y + w.z * c.z + w.w * c.w;
        }
        acc = wave_reduce_sum(acc);
        if (lane == 0) { acc += out_b[row]; logits[row] = acc; }
    }
    if (lane == 0) wmax[wib] = (row < VOCAB) ? acc : -INFINITY;
    __syncthreads();
    if (threadIdx.x == 0)
        blockmax[blockIdx.x] = fmaxf(fmaxf(wmax[0], wmax[1]), fmaxf(wmax[2], wmax[3]));
}

// K8b: reduce 12565 block maxima -> single float
__global__ __launch_bounds__(1024) void k_maxreduce(const float* __restrict__ blockmax,
                                                    float* __restrict__ maxcell) {
    __shared__ float sm[1024];
    int t = threadIdx.x;
    float m = -INFINITY;
    for (int i = t; i < LOGIT_BLOCKS; i += 1024) m = fmaxf(m, blockmax[i]);
    sm[t] = m;
    __syncthreads();
    for (int s = 512; s > 0; s >>= 1) { if (t < s) sm[t] = fmaxf(sm[t], sm[t + s]); __syncthreads(); }
    if (t == 0) maxcell[0] = sm[0];
}

// K9: partial sums of exp(logit - max); 128 blocks
__global__ void k_sumexp(const float* __restrict__ logits, const float* __restrict__ maxcell,
                         float* __restrict__ partials) {
    __shared__ float sm[4];
    float m = maxcell[0];
    float acc = 0.f;
    for (int v = blockIdx.x * blockDim.x + threadIdx.x; v < VOCAB; v += gridDim.x * blockDim.x)
        acc += expf(logits[v] - m);
    acc = wave_reduce_sum(acc);
    int wib = threadIdx.x >> 6, lane = threadIdx.x & 63;
    if (lane == 0) sm[wib] = acc;
    __syncthreads();
    if (threadIdx.x == 0) partials[blockIdx.x] = sm[0] + sm[1] + sm[2] + sm[3];
}

// K10: lse = max + log(sum(partials))
__global__ void k_finalize(const float* __restrict__ partials, const float* __restrict__ maxcell,
                           float* __restrict__ lse) {
    __shared__ float a[2];
    float v = partials[threadIdx.x];  // 128 threads
    v = wave_reduce_sum(v);
    if ((threadIdx.x & 63) == 0) a[threadIdx.x >> 6] = v;
    __syncthreads();
    if (threadIdx.x == 0) lse[0] = maxcell[0] + logf(a[0] + a[1]);
}

// K11: out[v] = logits[v] - lse  (in place on d_out)
__global__ void k_writeout(float* __restrict__ out, const float* __restrict__ lse) {
    int v = blockIdx.x * blockDim.x + threadIdx.x;
    if (v < VOCAB) out[v] -= lse[0];
}

extern "C" void kernel_launch(void* const* d_in, const int* in_sizes, int n_in,
                              void* d_out, int out_size, void* d_ws, size_t ws_size,
                              hipStream_t stream) {
    const int*   tok     = (const int*)d_in[0];
    const float* hidden  = (const float*)d_in[1];
    const float* E       = (const float*)d_in[2];
    const float* emb     = (const float*)d_in[3];
    const float* attn_W  = (const float*)d_in[4];
    const float* attn_b  = (const float*)d_in[5];
    const float* comb_W  = (const float*)d_in[6];
    const float* comb_b  = (const float*)d_in[7];
    const float* W_ih    = (const float*)d_in[8];
    const float* W_hh    = (const float*)d_in[9];
    const float* b_ih    = (const float*)d_in[10];
    const float* b_hh    = (const float*)d_in[11];
    const float* out_W   = (const float*)d_in[12];
    const float* out_b   = (const float*)d_in[13];

    float* out       = (float*)d_out;          // [0, VOCAB): log-probs
    float* hnew_out  = out + VOCAB;            // [VOCAB, VOCAB+HID): h_new
    float* attnw_out = out + VOCAB + HID;      // [.., +MAXLEN): attn_weights

    float* ws        = (float*)d_ws;
    float* scores    = ws + WS_SCORES;
    float* attnw_ws  = ws + WS_ATTNW;
    float* applied   = ws + WS_APPLIED;
    float* x         = ws + WS_X;
    float* gi        = ws + WS_GI;
    float* gh        = ws + WS_GH;
    float* hnew_ws   = ws + WS_HNEW;
    float* maxcell   = ws + WS_MAXCELL;
    float* lse       = ws + WS_LSE;
    float* sumpart   = ws + WS_SUMPART;
    float* partials  = ws + WS_PARTIALS;       // attn partials, later blockmax
    float* blockmax  = ws + WS_PARTIALS;       // reuse (attn partials dead by then)

    k_attn_scores<<<MAXLEN / 4, 256, 0, stream>>>(emb, tok, hidden, attn_W, attn_b, scores);
    k_softmax2048<<<1, 1024, 0, stream>>>(scores, attnw_out, attnw_ws);
    k_attn_apply_partial<<<64, 256, 0, stream>>>(E, attnw_ws, partials);
    k_attn_apply_reduce<<<4, 256, 0, stream>>>(partials, applied);
    k_comb<<<HID / 4, 256, 0, stream>>>(emb, tok, applied, comb_W, comb_b, x);
    k_gru_gemv<<<(6 * HID) / 4, 256, 0, stream>>>(W_ih, W_hh, b_ih, b_hh, x, hidden, gi, gh);
    k_gru_gate<<<HID / 256, 256, 0, stream>>>(gi, gh, hidden, hnew_out, hnew_ws);
    k_logits<<<LOGIT_BLOCKS, 256, 0, stream>>>(hnew_ws, out_W, out_b, out, blockmax);
    k_maxreduce<<<1, 1024, 0, stream>>>(blockmax, maxcell);
    k_sumexp<<<128, 256, 0, stream>>>(out, maxcell, sumpart);
    k_finalize<<<1, 128, 0, stream>>>(sumpart, maxcell, lse);
    k_writeout<<<(VOCAB + 255) / 256, 256, 0, stream>>>(out, lse);
}